// Round 2
// baseline (316.507 us; speedup 1.0000x reference)
//
#include <hip/hip_runtime.h>

typedef __bf16 bf16;
typedef __attribute__((ext_vector_type(4))) __bf16 bf16x4;
typedef __attribute__((ext_vector_type(8))) __bf16 bf16x8;
typedef __attribute__((ext_vector_type(4))) float f32x4;

#define NEG_INF_F (-1e30f)

// ---------------- workspace layout (bytes) ----------------
// flag:    [0, 4)
// packed:  [1024, 1024+524288)            2048 rows x 64 uint words
// Qp bf16: [525312, +4 MiB)
// Kp bf16: [4719616, +4 MiB)
// Vp bf16: [8913920, +4 MiB)
// AO bf16: [13108224, +4 MiB)   total ~16.5 MiB
#define OFF_MASK 1024
#define OFF_Q    525312
#define OFF_K    4719616
#define OFF_V    8913920
#define OFF_AO   13108224

// ---------------- mask element-width detection ----------------
// bool->uint8: bytes at off%4!=0 are random 0/1  -> width 1
// int32:       bytes at off%4!=0 are 0, off%8>=4 random -> width 4
// int64:       both zero -> width 8
__global__ void detect_width_kernel(const unsigned char* __restrict__ m,
                                    unsigned int* __restrict__ flag) {
  __shared__ unsigned int s13, s47;
  const int tid = threadIdx.x;
  if (tid == 0) { s13 = 0u; s47 = 0u; }
  __syncthreads();
  unsigned int a13 = 0u, a47 = 0u;
  const int base = tid * 64;
  for (int j = 0; j < 64; ++j) {
    const int off = base + j;
    const unsigned int b = m[off];
    if (off & 3) a13 |= b;
    if (off & 4) a47 |= b;
  }
  if (a13) atomicOr(&s13, 1u);
  if (a47) atomicOr(&s47, 1u);
  __syncthreads();
  if (tid == 0) flag[0] = s13 ? 1u : (s47 ? 4u : 8u);
}

// ---------------- pack mask to 1 bit/entry via ballot ----------------
__global__ void pack_mask_kernel(const unsigned char* __restrict__ srcb,
                                 const unsigned int* __restrict__ flag,
                                 unsigned int* __restrict__ dst) {
  const unsigned int width = flag[0];
  const int lane = threadIdx.x & 63;
  const size_t stride = (size_t)gridDim.x * blockDim.x;
  for (size_t e = (size_t)blockIdx.x * blockDim.x + threadIdx.x;
       e < 2048ull * 2048ull; e += stride) {
    unsigned int v;
    if (width == 4u)      v = ((const unsigned int*)srcb)[e];
    else if (width == 1u) v = srcb[e];
    else                  v = (unsigned int)((const unsigned long long*)srcb)[e];
    const unsigned long long bal = __ballot(v & 1u);
    if (lane == 0)       dst[e >> 5] = (unsigned int)bal;
    else if (lane == 32) dst[e >> 5] = (unsigned int)(bal >> 32);
  }
}

// ---------------- GEMM C = A * B^T  (A [M,1024], B [N=1024,1024] row-major) ----------------
// 128x128 tile, BK=32, 4 waves (2x2 of 64x64), 16x16x32 bf16 MFMA.
// LDS rows padded to 40 bf16 (80B stride: 16B-aligned, banks spread).
template <typename TA, typename TC>
__device__ __forceinline__ void gemm_nt_128(const TA* __restrict__ A,
                                            const float* __restrict__ B,
                                            TC* __restrict__ C,
                                            int brow, int bcol) {
  constexpr int Kdim = 1024, Ndim = 1024;
  __shared__ bf16 As[128][40];
  __shared__ bf16 Bs[128][40];
  const int tid = threadIdx.x;
  const int lane = tid & 63, w = tid >> 6;
  const int wr = w >> 1, wc = w & 1;
  const int l15 = lane & 15, l4 = lane >> 4;
  const int lr = tid >> 3, lc = (tid & 7) * 4;
  const f32x4 vzero = {0.f, 0.f, 0.f, 0.f};
  f32x4 acc[4][4];
#pragma unroll
  for (int m = 0; m < 4; ++m)
#pragma unroll
    for (int n = 0; n < 4; ++n) acc[m][n] = vzero;

  for (int kt = 0; kt < Kdim; kt += 32) {
#pragma unroll
    for (int it = 0; it < 4; ++it) {
      const int r = lr + it * 32;
      bf16x4 a4, b4;
      if constexpr (sizeof(TA) == 4) {
        const float4 av = *(const float4*)&A[(size_t)(brow + r) * Kdim + kt + lc];
        a4[0] = (bf16)av.x; a4[1] = (bf16)av.y; a4[2] = (bf16)av.z; a4[3] = (bf16)av.w;
      } else {
        a4 = *(const bf16x4*)&A[(size_t)(brow + r) * Kdim + kt + lc];
      }
      const float4 bv = *(const float4*)&B[(size_t)(bcol + r) * Kdim + kt + lc];
      b4[0] = (bf16)bv.x; b4[1] = (bf16)bv.y; b4[2] = (bf16)bv.z; b4[3] = (bf16)bv.w;
      *(bf16x4*)&As[r][lc] = a4;
      *(bf16x4*)&Bs[r][lc] = b4;
    }
    __syncthreads();
    bf16x8 af[4], bfr[4];
#pragma unroll
    for (int m = 0; m < 4; ++m)
      af[m] = *(const bf16x8*)&As[wr * 64 + m * 16 + l15][l4 * 8];
#pragma unroll
    for (int n = 0; n < 4; ++n)
      bfr[n] = *(const bf16x8*)&Bs[wc * 64 + n * 16 + l15][l4 * 8];
#pragma unroll
    for (int m = 0; m < 4; ++m)
#pragma unroll
      for (int n = 0; n < 4; ++n)
        acc[m][n] = __builtin_amdgcn_mfma_f32_16x16x32_bf16(af[m], bfr[n], acc[m][n], 0, 0, 0);
    __syncthreads();
  }
#pragma unroll
  for (int m = 0; m < 4; ++m)
#pragma unroll
    for (int n = 0; n < 4; ++n)
#pragma unroll
      for (int j = 0; j < 4; ++j) {
        const int row = brow + wr * 64 + m * 16 + l4 * 4 + j;
        const int col = bcol + wc * 64 + n * 16 + l15;
        C[(size_t)row * Ndim + col] = (TC)acc[m][n][j];
      }
}

__global__ __launch_bounds__(256) void gemm_qkv_kernel(
    const float* __restrict__ Aq, const float* __restrict__ Ak, const float* __restrict__ Av,
    const float* __restrict__ Bq, const float* __restrict__ Bk, const float* __restrict__ Bv,
    bf16* __restrict__ Cq, bf16* __restrict__ Ck, bf16* __restrict__ Cv) {
  const int z = blockIdx.z;
  const float* A = (z == 0) ? Aq : (z == 1) ? Ak : Av;
  const float* B = (z == 0) ? Bq : (z == 1) ? Bk : Bv;
  bf16* C = (z == 0) ? Cq : (z == 1) ? Ck : Cv;
  gemm_nt_128<float, bf16>(A, B, C, blockIdx.y * 128, blockIdx.x * 128);
}

__global__ __launch_bounds__(256) void gemm_out_kernel(const bf16* __restrict__ A,
                                                       const float* __restrict__ B,
                                                       float* __restrict__ C) {
  gemm_nt_128<bf16, float>(A, B, C, blockIdx.y * 128, blockIdx.x * 128);
}

// ---------------- flash attention ----------------
// block = (64 q-rows, 1 head); 4 waves x 16 q-rows; KV tiles of 32.
// QK^T: A=Q frags (registers), B=K tile (LDS row-major, contiguous-k reads).
// PV:   A=P (LDS round-trip to reach A-operand layout), B=V^T (transposed at stage).
__global__ __launch_bounds__(256) void flash_attn_kernel(
    const bf16* __restrict__ Qp, const bf16* __restrict__ Kp, const bf16* __restrict__ Vp,
    const unsigned int* __restrict__ mwg, bf16* __restrict__ AO) {
  const int qb = blockIdx.x * 64;
  const int h = blockIdx.y;
  const int tid = threadIdx.x;
  const int lane = tid & 63, w = tid >> 6;
  const int l15 = lane & 15, l4 = lane >> 4;
  __shared__ bf16 Ks[32][72];           // [kv][d], 144B stride: aligned + spread
  __shared__ bf16 Vt[64][40];           // [d][kv]
  __shared__ unsigned int mwords[64];   // one uint per q-row of the block
  __shared__ bf16 Ps[4][16][40];        // per-wave P tile [q][kv]

  const bf16* Qrow = Qp + (size_t)(qb + w * 16 + l15) * 1024 + h * 64;
  const bf16x8 qf0 = *(const bf16x8*)(Qrow + l4 * 8);
  const bf16x8 qf1 = *(const bf16x8*)(Qrow + 32 + l4 * 8);

  const f32x4 vzero = {0.f, 0.f, 0.f, 0.f};
  f32x4 oacc[4] = {vzero, vzero, vzero, vzero};
  float m_i[4], l_i[4];
#pragma unroll
  for (int j = 0; j < 4; ++j) { m_i[j] = NEG_INF_F; l_i[j] = 0.f; }

  const int sr = tid >> 3, sc8 = (tid & 7) * 8;
  for (int kv0 = 0; kv0 < 2048; kv0 += 32) {
    // ---- stage K, V^T, mask words ----
    const bf16x8 kv8 = *(const bf16x8*)(Kp + (size_t)(kv0 + sr) * 1024 + h * 64 + sc8);
    const bf16x8 vv8 = *(const bf16x8*)(Vp + (size_t)(kv0 + sr) * 1024 + h * 64 + sc8);
    *(bf16x8*)&Ks[sr][sc8] = kv8;
#pragma unroll
    for (int j = 0; j < 8; ++j) Vt[sc8 + j][sr] = vv8[j];
    if (tid < 64) mwords[tid] = mwg[(size_t)(qb + tid) * 64 + (kv0 >> 5)];
    __syncthreads();

    // ---- QK^T: 16q x 32kv, fp32 acc ----
    f32x4 s0 = vzero, s1 = vzero;
    {
      bf16x8 kf;
      kf = *(const bf16x8*)&Ks[l15][l4 * 8];
      s0 = __builtin_amdgcn_mfma_f32_16x16x32_bf16(qf0, kf, s0, 0, 0, 0);
      kf = *(const bf16x8*)&Ks[l15][32 + l4 * 8];
      s0 = __builtin_amdgcn_mfma_f32_16x16x32_bf16(qf1, kf, s0, 0, 0, 0);
      kf = *(const bf16x8*)&Ks[16 + l15][l4 * 8];
      s1 = __builtin_amdgcn_mfma_f32_16x16x32_bf16(qf0, kf, s1, 0, 0, 0);
      kf = *(const bf16x8*)&Ks[16 + l15][32 + l4 * 8];
      s1 = __builtin_amdgcn_mfma_f32_16x16x32_bf16(qf1, kf, s1, 0, 0, 0);
    }

    // ---- mask + online softmax (rows j; cols across the 16-lane group) ----
#pragma unroll
    for (int j = 0; j < 4; ++j) {
      const unsigned int word = mwords[w * 16 + l4 * 4 + j];
      const float a = ((word >> l15) & 1u) ? NEG_INF_F : s0[j] * 0.125f;
      const float b = ((word >> (16 + l15)) & 1u) ? NEG_INF_F : s1[j] * 0.125f;
      float t = fmaxf(a, b);
#pragma unroll
      for (int d = 1; d < 16; d <<= 1) t = fmaxf(t, __shfl_xor(t, d));
      const float mn = fmaxf(m_i[j], t);
      const float sc = __expf(m_i[j] - mn);
      const float pa = __expf(a - mn);
      const float pb = __expf(b - mn);
      float rs = pa + pb;
#pragma unroll
      for (int d = 1; d < 16; d <<= 1) rs += __shfl_xor(rs, d);
      l_i[j] = l_i[j] * sc + rs;
      m_i[j] = mn;
#pragma unroll
      for (int n = 0; n < 4; ++n) oacc[n][j] *= sc;
      Ps[w][l4 * 4 + j][l15] = (bf16)pa;
      Ps[w][l4 * 4 + j][16 + l15] = (bf16)pb;
    }

    // ---- PV: O += P[16x32] * V[32x64] ----
    const bf16x8 pf = *(const bf16x8*)&Ps[w][l15][l4 * 8];
#pragma unroll
    for (int n = 0; n < 4; ++n) {
      const bf16x8 vf = *(const bf16x8*)&Vt[n * 16 + l15][l4 * 8];
      oacc[n] = __builtin_amdgcn_mfma_f32_16x16x32_bf16(pf, vf, oacc[n], 0, 0, 0);
    }
    __syncthreads();
  }

#pragma unroll
  for (int n = 0; n < 4; ++n)
#pragma unroll
    for (int j = 0; j < 4; ++j) {
      const float val = oacc[n][j] / l_i[j];
      AO[(size_t)(qb + w * 16 + l4 * 4 + j) * 1024 + h * 64 + n * 16 + l15] = (bf16)val;
    }
}

// ---------------- launch ----------------
extern "C" void kernel_launch(void* const* d_in, const int* in_sizes, int n_in,
                              void* d_out, int out_size, void* d_ws, size_t ws_size,
                              hipStream_t stream) {
  const float* q = (const float*)d_in[0];
  const float* k = (const float*)d_in[1];
  const float* v = (const float*)d_in[2];
  const unsigned char* mask = (const unsigned char*)d_in[3];
  const float* Wq = (const float*)d_in[4];
  const float* Wk = (const float*)d_in[5];
  const float* Wv = (const float*)d_in[6];
  const float* Wo = (const float*)d_in[7];
  float* out = (float*)d_out;

  char* ws = (char*)d_ws;
  unsigned int* flag = (unsigned int*)ws;
  unsigned int* mpacked = (unsigned int*)(ws + OFF_MASK);
  bf16* Qp = (bf16*)(ws + OFF_Q);
  bf16* Kp = (bf16*)(ws + OFF_K);
  bf16* Vp = (bf16*)(ws + OFF_V);
  bf16* AO = (bf16*)(ws + OFF_AO);

  detect_width_kernel<<<1, 256, 0, stream>>>(mask, flag);
  pack_mask_kernel<<<2048, 256, 0, stream>>>(mask, flag, mpacked);
  gemm_qkv_kernel<<<dim3(8, 16, 3), 256, 0, stream>>>(q, k, v, Wq, Wk, Wv, Qp, Kp, Vp);
  flash_attn_kernel<<<dim3(32, 16), 256, 0, stream>>>(Qp, Kp, Vp, mpacked, AO);
  gemm_out_kernel<<<dim3(8, 16), 256, 0, stream>>>(AO, Wo, out);
}

// Round 4
// 225.073 us; speedup vs baseline: 1.4062x; 1.4062x over previous
//
#include <hip/hip_runtime.h>

typedef __bf16 bf16;
typedef __attribute__((ext_vector_type(8))) __bf16 bf16x8;
typedef __attribute__((ext_vector_type(4))) float f32x4;

#define NEG_INF_F (-1e30f)

// ---------------- workspace layout (bytes) ----------------
#define OFF_MASK 1024                      // 512 KiB packed mask
#define OFF_WQ   (1024 + 524288)           // 4 x 2 MiB bf16 weights
#define OFF_WK   (OFF_WQ + 2097152)
#define OFF_WV   (OFF_WK + 2097152)
#define OFF_WO   (OFF_WV + 2097152)
#define OFF_QP   (OFF_WO + 2097152)        // 3 x 4 MiB bf16 projections
#define OFF_KP   (OFF_QP + 4194304)
#define OFF_VP   (OFF_KP + 4194304)
#define OFF_AO   (OFF_VP + 4194304)        // 4 MiB attn output; total ~25.7 MiB

// ---------------- global_load_lds (width 16) ----------------
typedef __attribute__((address_space(1))) const unsigned int as1_u32;
typedef __attribute__((address_space(3))) unsigned int as3_u32;
__device__ __forceinline__ void gload16(const void* g, void* l) {
  __builtin_amdgcn_global_load_lds((as1_u32*)g, (as3_u32*)l, 16, 0, 0);
}

__device__ __forceinline__ bf16x8 cvt8(const float4 a, const float4 b) {
  bf16x8 o;
  o[0] = (bf16)a.x; o[1] = (bf16)a.y; o[2] = (bf16)a.z; o[3] = (bf16)a.w;
  o[4] = (bf16)b.x; o[5] = (bf16)b.y; o[6] = (bf16)b.z; o[7] = (bf16)b.w;
  return o;
}

// ---------------- mask width detect + pack (unchanged, proven) ----------------
__global__ void detect_width_kernel(const unsigned char* __restrict__ m,
                                    unsigned int* __restrict__ flag) {
  __shared__ unsigned int s13, s47;
  const int tid = threadIdx.x;
  if (tid == 0) { s13 = 0u; s47 = 0u; }
  __syncthreads();
  unsigned int a13 = 0u, a47 = 0u;
  const int base = tid * 64;
  for (int j = 0; j < 64; ++j) {
    const int off = base + j;
    const unsigned int b = m[off];
    if (off & 3) a13 |= b;
    if (off & 4) a47 |= b;
  }
  if (a13) atomicOr(&s13, 1u);
  if (a47) atomicOr(&s47, 1u);
  __syncthreads();
  if (tid == 0) flag[0] = s13 ? 1u : (s47 ? 4u : 8u);
}

__global__ void pack_mask_kernel(const unsigned char* __restrict__ srcb,
                                 const unsigned int* __restrict__ flag,
                                 unsigned int* __restrict__ dst) {
  const unsigned int width = flag[0];
  const int lane = threadIdx.x & 63;
  const size_t stride = (size_t)gridDim.x * blockDim.x;
  for (size_t e = (size_t)blockIdx.x * blockDim.x + threadIdx.x;
       e < 2048ull * 2048ull; e += stride) {
    unsigned int v;
    if (width == 4u)      v = ((const unsigned int*)srcb)[e];
    else if (width == 1u) v = srcb[e];
    else                  v = (unsigned int)((const unsigned long long*)srcb)[e];
    const unsigned long long bal = __ballot(v & 1u);
    if (lane == 0)       dst[e >> 5] = (unsigned int)bal;
    else if (lane == 32) dst[e >> 5] = (unsigned int)(bal >> 32);
  }
}

// ---------------- fp32 -> bf16 weight convert ----------------
__global__ __launch_bounds__(256) void convert_w_kernel(
    const float* __restrict__ W0, const float* __restrict__ W1,
    const float* __restrict__ W2, const float* __restrict__ W3,
    bf16* __restrict__ D0, bf16* __restrict__ D1,
    bf16* __restrict__ D2, bf16* __restrict__ D3) {
  const int z = blockIdx.y;
  const float* s = (z == 0) ? W0 : (z == 1) ? W1 : (z == 2) ? W2 : W3;
  bf16* d = (z == 0) ? D0 : (z == 1) ? D1 : (z == 2) ? D2 : D3;
  const int i = blockIdx.x * 256 + threadIdx.x;   // 131072 threads x 8 elems = 1M
  const float4 x0 = ((const float4*)s)[i * 2];
  const float4 x1 = ((const float4*)s)[i * 2 + 1];
  ((bf16x8*)d)[i] = cvt8(x0, x1);
}

// ---------------- GEMM C = A * B^T ; BM=64, BN=128, BK=64, 4 waves (2x2) ----------------
// B always bf16 via global_load_lds, linear LDS + source-swizzle (m201 both-sides rule).
// A: fp32 -> reg-staged into padded LDS; bf16 -> global_load_lds like B.
template <bool AF32, typename TC>
__device__ __forceinline__ void gemm_body(const void* Avoid, const bf16* __restrict__ B,
                                          TC* __restrict__ C, int brow, int bcol) {
  __shared__ __align__(16) bf16 AsBuf[64 * 72];   // fp32 path: [64][72]; bf16 path: [64][64] linear
  __shared__ __align__(16) bf16 Bs[128 * 64];     // linear, source-swizzled
  const int tid = threadIdx.x;
  const int lane = tid & 63, w = tid >> 6;
  const int wr = w >> 1, wc = w & 1;
  const int l15 = lane & 15, l4 = lane >> 4;
  const int srow = lane >> 3;                     // 0..7
  const int sgrp = (lane & 7) ^ srow;             // swizzled source k-group

  f32x4 acc[2][4] = {};

  for (int kt = 0; kt < 1024; kt += 64) {
    __syncthreads();
    // B: 4 wave-passes of 8 rows x 128B
#pragma unroll
    for (int p = 0; p < 4; ++p) {
      const int rb = w * 32 + p * 8;
      gload16(B + (size_t)(bcol + rb + srow) * 1024 + kt + sgrp * 8, &Bs[rb * 64]);
    }
    if constexpr (AF32) {
      const float* A = (const float*)Avoid;
      const int row = tid >> 2, c16 = (tid & 3) * 16;
      const float4* ap = (const float4*)(A + (size_t)(brow + row) * 1024 + kt + c16);
      const float4 x0 = ap[0], x1 = ap[1], x2 = ap[2], x3 = ap[3];
      *(bf16x8*)&AsBuf[row * 72 + c16] = cvt8(x0, x1);
      *(bf16x8*)&AsBuf[row * 72 + c16 + 8] = cvt8(x2, x3);
    } else {
      const bf16* A = (const bf16*)Avoid;
#pragma unroll
      for (int p = 0; p < 2; ++p) {
        const int rb = w * 16 + p * 8;
        gload16(A + (size_t)(brow + rb + srow) * 1024 + kt + sgrp * 8, &AsBuf[rb * 64]);
      }
    }
    __syncthreads();

    bf16x8 af0[2], af1[2], b0[4], b1[4];
#pragma unroll
    for (int m = 0; m < 2; ++m) {
      const int row = wr * 32 + m * 16 + l15;
      if constexpr (AF32) {
        af0[m] = *(const bf16x8*)&AsBuf[row * 72 + l4 * 8];
        af1[m] = *(const bf16x8*)&AsBuf[row * 72 + 32 + l4 * 8];
      } else {
        const int g0 = l4 ^ (l15 & 7);
        af0[m] = *(const bf16x8*)&AsBuf[row * 64 + g0 * 8];
        af1[m] = *(const bf16x8*)&AsBuf[row * 64 + (g0 ^ 4) * 8];
      }
    }
#pragma unroll
    for (int n = 0; n < 4; ++n) {
      const int row = wc * 64 + n * 16 + l15;
      const int g0 = l4 ^ (l15 & 7);
      b0[n] = *(const bf16x8*)&Bs[row * 64 + g0 * 8];
      b1[n] = *(const bf16x8*)&Bs[row * 64 + (g0 ^ 4) * 8];
    }
#pragma unroll
    for (int m = 0; m < 2; ++m)
#pragma unroll
      for (int n = 0; n < 4; ++n) {
        acc[m][n] = __builtin_amdgcn_mfma_f32_16x16x32_bf16(af0[m], b0[n], acc[m][n], 0, 0, 0);
        acc[m][n] = __builtin_amdgcn_mfma_f32_16x16x32_bf16(af1[m], b1[n], acc[m][n], 0, 0, 0);
      }
  }
#pragma unroll
  for (int m = 0; m < 2; ++m)
#pragma unroll
    for (int n = 0; n < 4; ++n)
#pragma unroll
      for (int j = 0; j < 4; ++j) {
        const int row = brow + wr * 32 + m * 16 + l4 * 4 + j;
        const int col = bcol + wc * 64 + n * 16 + l15;
        C[(size_t)row * 1024 + col] = (TC)acc[m][n][j];
      }
}

__global__ __launch_bounds__(256) void gemm_qkv_kernel(
    const float* __restrict__ Aq, const float* __restrict__ Ak, const float* __restrict__ Av,
    const bf16* __restrict__ Bq, const bf16* __restrict__ Bk, const bf16* __restrict__ Bv,
    bf16* __restrict__ Cq, bf16* __restrict__ Ck, bf16* __restrict__ Cv) {
  const int z = blockIdx.z;
  const float* A = (z == 0) ? Aq : (z == 1) ? Ak : Av;
  const bf16* B = (z == 0) ? Bq : (z == 1) ? Bk : Bv;
  bf16* C = (z == 0) ? Cq : (z == 1) ? Ck : Cv;
  gemm_body<true, bf16>(A, B, C, blockIdx.y * 64, blockIdx.x * 128);
}

__global__ __launch_bounds__(256) void gemm_out_kernel(const bf16* __restrict__ A,
                                                       const bf16* __restrict__ B,
                                                       float* __restrict__ C) {
  gemm_body<false, float>(A, B, C, blockIdx.y * 64, blockIdx.x * 128);
}

// ---------------- flash attention: 64 q-rows x 1 head, KVBLK=64, dbuf, 1 barrier/tile --------
// K: global_load_lds, linear [64][64], source k-group swizzled by row&7.
// V: reg-staged transpose Vt[d][kv] with kv-group XOR (d>>3) swizzle (conflict-free both sides).
__global__ __launch_bounds__(256) void flash_attn_kernel(
    const bf16* __restrict__ Qp, const bf16* __restrict__ Kp, const bf16* __restrict__ Vp,
    const unsigned int* __restrict__ mwg, bf16* __restrict__ AO) {
  const int h = blockIdx.x;            // XCD = h % 8 -> per-XCD L2 holds 2 heads' K/V
  const int qb = blockIdx.y * 64;
  const int tid = threadIdx.x;
  const int lane = tid & 63, w = tid >> 6;
  const int l15 = lane & 15, l4 = lane >> 4;

  __shared__ __align__(16) bf16 Ks[2][64 * 64];
  __shared__ __align__(16) bf16 Vt[2][64 * 72];
  __shared__ unsigned int Msk[2][64][2];
  __shared__ __align__(16) bf16 Ps[4][16 * 72];

  // Q fragments (A-operand: row=l15, k=l4*8+j)
  const bf16* Qrow = Qp + (size_t)(qb + w * 16 + l15) * 1024 + h * 64;
  const bf16x8 qf0 = *(const bf16x8*)(Qrow + l4 * 8);
  const bf16x8 qf1 = *(const bf16x8*)(Qrow + 32 + l4 * 8);

  f32x4 oacc[4] = {};
  float m_i[4], l_i[4];
#pragma unroll
  for (int j = 0; j < 4; ++j) { m_i[j] = NEG_INF_F; l_i[j] = 0.f; }

  const int srow = lane >> 3, sgrp = (lane & 7) ^ srow;   // K gload source indices
  const int vr = tid >> 3, vc8 = (tid & 7) * 8;           // V staging indices
  const int vg0 = ((vr >> 3) ^ (tid & 7)) & 7;            // Vt write group (pass0)

  // ---- prologue: prefetch tile 0 ----
  bf16x8 vpre0, vpre1; unsigned int mpre = 0;
#pragma unroll
  for (int p = 0; p < 2; ++p) {
    const int rb = w * 16 + p * 8;
    gload16(Kp + (size_t)(rb + srow) * 1024 + h * 64 + sgrp * 8, &Ks[0][rb * 64]);
  }
  vpre0 = *(const bf16x8*)(Vp + (size_t)vr * 1024 + h * 64 + vc8);
  vpre1 = *(const bf16x8*)(Vp + (size_t)(vr + 32) * 1024 + h * 64 + vc8);
  if (tid < 128) mpre = mwg[(size_t)(qb + (tid >> 1)) * 64 + (tid & 1)];

  for (int t = 0; t < 32; ++t) {
    const int cur = t & 1;
    // commit prefetched V (swizzled transpose) + mask to LDS
#pragma unroll
    for (int j = 0; j < 8; ++j) {
      const int d = vc8 + j;
      Vt[cur][d * 72 + vg0 * 8 + (vr & 7)] = vpre0[j];
      Vt[cur][d * 72 + (vg0 ^ 4) * 8 + (vr & 7)] = vpre1[j];
    }
    if (tid < 128) Msk[cur][tid >> 1][tid & 1] = mpre;
    __syncthreads();   // drains K gloads (vmcnt) + LDS writes for buf[cur]

    // prefetch tile t+1 into buf[cur^1] / regs (hidden under compute)
    if (t + 1 < 32) {
      const int kvn = (t + 1) * 64;
#pragma unroll
      for (int p = 0; p < 2; ++p) {
        const int rb = w * 16 + p * 8;
        gload16(Kp + (size_t)(kvn + rb + srow) * 1024 + h * 64 + sgrp * 8,
                &Ks[cur ^ 1][rb * 64]);
      }
      vpre0 = *(const bf16x8*)(Vp + (size_t)(kvn + vr) * 1024 + h * 64 + vc8);
      vpre1 = *(const bf16x8*)(Vp + (size_t)(kvn + vr + 32) * 1024 + h * 64 + vc8);
      if (tid < 128) mpre = mwg[(size_t)(qb + (tid >> 1)) * 64 + (t + 1) * 2 + (tid & 1)];
    }

    // ---- QK^T: 16q x 64kv ----
    f32x4 s[4] = {};
    const int kg0 = l4 ^ (l15 & 7);
#pragma unroll
    for (int g = 0; g < 4; ++g) {
      const int krow = g * 16 + l15;
      const bf16x8 kf0 = *(const bf16x8*)&Ks[cur][krow * 64 + kg0 * 8];
      s[g] = __builtin_amdgcn_mfma_f32_16x16x32_bf16(qf0, kf0, s[g], 0, 0, 0);
      const bf16x8 kf1 = *(const bf16x8*)&Ks[cur][krow * 64 + (kg0 ^ 4) * 8];
      s[g] = __builtin_amdgcn_mfma_f32_16x16x32_bf16(qf1, kf1, s[g], 0, 0, 0);
    }

    // ---- mask + online softmax ----
#pragma unroll
    for (int j = 0; j < 4; ++j) {
      const int qrow = w * 16 + l4 * 4 + j;
      const unsigned int u0 = Msk[cur][qrow][0];
      const unsigned int u1 = Msk[cur][qrow][1];
      const float a0 = ((u0 >> l15) & 1u)        ? NEG_INF_F : s[0][j] * 0.125f;
      const float a1 = ((u0 >> (16 + l15)) & 1u) ? NEG_INF_F : s[1][j] * 0.125f;
      const float a2 = ((u1 >> l15) & 1u)        ? NEG_INF_F : s[2][j] * 0.125f;
      const float a3 = ((u1 >> (16 + l15)) & 1u) ? NEG_INF_F : s[3][j] * 0.125f;
      float t4 = fmaxf(fmaxf(a0, a1), fmaxf(a2, a3));
#pragma unroll
      for (int d = 1; d < 16; d <<= 1) t4 = fmaxf(t4, __shfl_xor(t4, d));
      const float mn = fmaxf(m_i[j], t4);
      const float sc = __expf(m_i[j] - mn);
      const float e0 = __expf(a0 - mn), e1 = __expf(a1 - mn);
      const float e2 = __expf(a2 - mn), e3 = __expf(a3 - mn);
      float rs = (e0 + e1) + (e2 + e3);
#pragma unroll
      for (int d = 1; d < 16; d <<= 1) rs += __shfl_xor(rs, d);
      l_i[j] = l_i[j] * sc + rs;
      m_i[j] = mn;
      oacc[0][j] *= sc; oacc[1][j] *= sc; oacc[2][j] *= sc; oacc[3][j] *= sc;
      bf16* prow = &Ps[w][(l4 * 4 + j) * 72];
      prow[l15] = (bf16)e0; prow[16 + l15] = (bf16)e1;
      prow[32 + l15] = (bf16)e2; prow[48 + l15] = (bf16)e3;
    }

    // ---- PV: O += P[16x64] * V[64x64] (wave-local P round trip) ----
    const bf16x8 pf0 = *(const bf16x8*)&Ps[w][l15 * 72 + l4 * 8];
    const bf16x8 pf1 = *(const bf16x8*)&Ps[w][l15 * 72 + 32 + l4 * 8];
#pragma unroll
    for (int n = 0; n < 4; ++n) {
      const int d = n * 16 + l15;
      const int vgr = l4 ^ ((2 * n + (l15 >> 3)) & 7);
      const bf16x8 vf0 = *(const bf16x8*)&Vt[cur][d * 72 + vgr * 8];
      oacc[n] = __builtin_amdgcn_mfma_f32_16x16x32_bf16(pf0, vf0, oacc[n], 0, 0, 0);
      const bf16x8 vf1 = *(const bf16x8*)&Vt[cur][d * 72 + (vgr ^ 4) * 8];
      oacc[n] = __builtin_amdgcn_mfma_f32_16x16x32_bf16(pf1, vf1, oacc[n], 0, 0, 0);
    }
  }

#pragma unroll
  for (int n = 0; n < 4; ++n)
#pragma unroll
    for (int j = 0; j < 4; ++j)
      AO[(size_t)(qb + w * 16 + l4 * 4 + j) * 1024 + h * 64 + n * 16 + l15] =
          (bf16)(oacc[n][j] / l_i[j]);
}

// ---------------- launch ----------------
extern "C" void kernel_launch(void* const* d_in, const int* in_sizes, int n_in,
                              void* d_out, int out_size, void* d_ws, size_t ws_size,
                              hipStream_t stream) {
  const float* q = (const float*)d_in[0];
  const float* k = (const float*)d_in[1];
  const float* v = (const float*)d_in[2];
  const unsigned char* mask = (const unsigned char*)d_in[3];
  const float* Wq = (const float*)d_in[4];
  const float* Wk = (const float*)d_in[5];
  const float* Wv = (const float*)d_in[6];
  const float* Wo = (const float*)d_in[7];
  float* out = (float*)d_out;

  char* ws = (char*)d_ws;
  unsigned int* flag = (unsigned int*)ws;
  unsigned int* mpacked = (unsigned int*)(ws + OFF_MASK);
  bf16* Wqb = (bf16*)(ws + OFF_WQ);
  bf16* Wkb = (bf16*)(ws + OFF_WK);
  bf16* Wvb = (bf16*)(ws + OFF_WV);
  bf16* Wob = (bf16*)(ws + OFF_WO);
  bf16* Qp = (bf16*)(ws + OFF_QP);
  bf16* Kp = (bf16*)(ws + OFF_KP);
  bf16* Vp = (bf16*)(ws + OFF_VP);
  bf16* AO = (bf16*)(ws + OFF_AO);

  detect_width_kernel<<<1, 256, 0, stream>>>(mask, flag);
  pack_mask_kernel<<<2048, 256, 0, stream>>>(mask, flag, mpacked);
  convert_w_kernel<<<dim3(512, 4), 256, 0, stream>>>(Wq, Wk, Wv, Wo, Wqb, Wkb, Wvb, Wob);
  gemm_qkv_kernel<<<dim3(8, 32, 3), 256, 0, stream>>>(q, k, v, Wqb, Wkb, Wvb, Qp, Kp, Vp);
  flash_attn_kernel<<<dim3(16, 32), 256, 0, stream>>>(Qp, Kp, Vp, mpacked, AO);
  gemm_out_kernel<<<dim3(8, 32), 256, 0, stream>>>(AO, Wob, out);
}

// Round 5
// 207.591 us; speedup vs baseline: 1.5247x; 1.0842x over previous
//
#include <hip/hip_runtime.h>

typedef __bf16 bf16;
typedef __attribute__((ext_vector_type(4))) __bf16 bf16x4;
typedef __attribute__((ext_vector_type(8))) __bf16 bf16x8;
typedef __attribute__((ext_vector_type(4))) float f32x4;

#define NEG_INF_F (-1e30f)

// ---------------- workspace layout (bytes) ----------------
#define OFF_MASK 1024                      // 512 KiB packed mask
#define OFF_WQ   (1024 + 524288)           // 4 x 2 MiB bf16 weights
#define OFF_WK   (OFF_WQ + 2097152)
#define OFF_WV   (OFF_WK + 2097152)
#define OFF_WO   (OFF_WV + 2097152)
#define OFF_QP   (OFF_WO + 2097152)        // 3 x 4 MiB bf16 projections
#define OFF_KP   (OFF_QP + 4194304)
#define OFF_VP   (OFF_KP + 4194304)
#define OFF_AO   (OFF_VP + 4194304)        // 4 MiB attn output; total ~25.7 MiB

// ---------------- global_load_lds (width 16) ----------------
typedef __attribute__((address_space(1))) const unsigned int as1_u32;
typedef __attribute__((address_space(3))) unsigned int as3_u32;
__device__ __forceinline__ void gload16(const void* g, void* l) {
  __builtin_amdgcn_global_load_lds((as1_u32*)g, (as3_u32*)l, 16, 0, 0);
}

__device__ __forceinline__ bf16x8 cvt8(const float4 a, const float4 b) {
  bf16x8 o;
  o[0] = (bf16)a.x; o[1] = (bf16)a.y; o[2] = (bf16)a.z; o[3] = (bf16)a.w;
  o[4] = (bf16)b.x; o[5] = (bf16)b.y; o[6] = (bf16)b.z; o[7] = (bf16)b.w;
  return o;
}

// ---------------- mask width detect + pack (unchanged, proven) ----------------
__global__ void detect_width_kernel(const unsigned char* __restrict__ m,
                                    unsigned int* __restrict__ flag) {
  __shared__ unsigned int s13, s47;
  const int tid = threadIdx.x;
  if (tid == 0) { s13 = 0u; s47 = 0u; }
  __syncthreads();
  unsigned int a13 = 0u, a47 = 0u;
  const int base = tid * 64;
  for (int j = 0; j < 64; ++j) {
    const int off = base + j;
    const unsigned int b = m[off];
    if (off & 3) a13 |= b;
    if (off & 4) a47 |= b;
  }
  if (a13) atomicOr(&s13, 1u);
  if (a47) atomicOr(&s47, 1u);
  __syncthreads();
  if (tid == 0) flag[0] = s13 ? 1u : (s47 ? 4u : 8u);
}

__global__ void pack_mask_kernel(const unsigned char* __restrict__ srcb,
                                 const unsigned int* __restrict__ flag,
                                 unsigned int* __restrict__ dst) {
  const unsigned int width = flag[0];
  const int lane = threadIdx.x & 63;
  const size_t stride = (size_t)gridDim.x * blockDim.x;
  for (size_t e = (size_t)blockIdx.x * blockDim.x + threadIdx.x;
       e < 2048ull * 2048ull; e += stride) {
    unsigned int v;
    if (width == 4u)      v = ((const unsigned int*)srcb)[e];
    else if (width == 1u) v = srcb[e];
    else                  v = (unsigned int)((const unsigned long long*)srcb)[e];
    const unsigned long long bal = __ballot(v & 1u);
    if (lane == 0)       dst[e >> 5] = (unsigned int)bal;
    else if (lane == 32) dst[e >> 5] = (unsigned int)(bal >> 32);
  }
}

// ---------------- fp32 -> bf16 weight convert ----------------
__global__ __launch_bounds__(256) void convert_w_kernel(
    const float* __restrict__ W0, const float* __restrict__ W1,
    const float* __restrict__ W2, const float* __restrict__ W3,
    bf16* __restrict__ D0, bf16* __restrict__ D1,
    bf16* __restrict__ D2, bf16* __restrict__ D3) {
  const int z = blockIdx.y;
  const float* s = (z == 0) ? W0 : (z == 1) ? W1 : (z == 2) ? W2 : W3;
  bf16* d = (z == 0) ? D0 : (z == 1) ? D1 : (z == 2) ? D2 : D3;
  const int i = blockIdx.x * 256 + threadIdx.x;
  const float4 x0 = ((const float4*)s)[i * 2];
  const float4 x1 = ((const float4*)s)[i * 2 + 1];
  ((bf16x8*)d)[i] = cvt8(x0, x1);
}

// ---------------- GEMM C = A * B^T ; BM=64, BN=128, BK=64, double-buffered ----------------
// 2-phase pipeline: stage(t+1) issued right after barrier, MFMA(t) under in-flight loads.
template <bool AF32, typename TC>
__device__ __forceinline__ void gemm_body(const void* Avoid, const bf16* __restrict__ B,
                                          TC* __restrict__ C, int brow, int bcol) {
  __shared__ __align__(16) bf16 As[2][64 * 72];   // AF32: stride 72 padded; else linear 64
  __shared__ __align__(16) bf16 Bs[2][128 * 64];  // linear, source-swizzled
  const int tid = threadIdx.x;
  const int lane = tid & 63, w = tid >> 6;
  const int wr = w >> 1, wc = w & 1;
  const int l15 = lane & 15, l4 = lane >> 4;
  const int srow = lane >> 3, sgrp = (lane & 7) ^ srow;
  const int arow = tid >> 2, ac16 = (tid & 3) * 16;

  f32x4 acc[2][4] = {};

  // prologue: stage tile 0 into buf 0
#pragma unroll
  for (int p = 0; p < 4; ++p)
    gload16(B + (size_t)(bcol + w * 32 + p * 8 + srow) * 1024 + sgrp * 8,
            &Bs[0][(w * 32 + p * 8) * 64]);
  if constexpr (AF32) {
    const float* A = (const float*)Avoid;
    const float4* ap = (const float4*)(A + (size_t)(brow + arow) * 1024 + ac16);
    const float4 x0 = ap[0], x1 = ap[1], x2 = ap[2], x3 = ap[3];
    *(bf16x8*)&As[0][arow * 72 + ac16] = cvt8(x0, x1);
    *(bf16x8*)&As[0][arow * 72 + ac16 + 8] = cvt8(x2, x3);
  } else {
    const bf16* A = (const bf16*)Avoid;
#pragma unroll
    for (int p = 0; p < 2; ++p)
      gload16(A + (size_t)(brow + w * 16 + p * 8 + srow) * 1024 + sgrp * 8,
              &As[0][(w * 16 + p * 8) * 64]);
  }

#pragma unroll 2
  for (int i = 0; i < 16; ++i) {
    const int cur = i & 1;
    __syncthreads();   // drains gloads + LDS writes for buf[cur]
    float4 x0, x1, x2, x3;
    if (i + 1 < 16) {  // issue next-tile staging; flies under MFMA below
      const int kt = (i + 1) * 64;
#pragma unroll
      for (int p = 0; p < 4; ++p)
        gload16(B + (size_t)(bcol + w * 32 + p * 8 + srow) * 1024 + kt + sgrp * 8,
                &Bs[cur ^ 1][(w * 32 + p * 8) * 64]);
      if constexpr (AF32) {
        const float* A = (const float*)Avoid;
        const float4* ap = (const float4*)(A + (size_t)(brow + arow) * 1024 + kt + ac16);
        x0 = ap[0]; x1 = ap[1]; x2 = ap[2]; x3 = ap[3];
      } else {
        const bf16* A = (const bf16*)Avoid;
#pragma unroll
        for (int p = 0; p < 2; ++p)
          gload16(A + (size_t)(brow + w * 16 + p * 8 + srow) * 1024 + kt + sgrp * 8,
                  &As[cur ^ 1][(w * 16 + p * 8) * 64]);
      }
    }
    const int g0 = l4 ^ (l15 & 7);
    bf16x8 a0[2], a1[2], b0[4], b1[4];
#pragma unroll
    for (int m = 0; m < 2; ++m) {
      const int row = wr * 32 + m * 16 + l15;
      if constexpr (AF32) {
        a0[m] = *(const bf16x8*)&As[cur][row * 72 + l4 * 8];
        a1[m] = *(const bf16x8*)&As[cur][row * 72 + 32 + l4 * 8];
      } else {
        a0[m] = *(const bf16x8*)&As[cur][row * 64 + g0 * 8];
        a1[m] = *(const bf16x8*)&As[cur][row * 64 + (g0 ^ 4) * 8];
      }
    }
#pragma unroll
    for (int n = 0; n < 4; ++n) {
      const int row = wc * 64 + n * 16 + l15;
      b0[n] = *(const bf16x8*)&Bs[cur][row * 64 + g0 * 8];
      b1[n] = *(const bf16x8*)&Bs[cur][row * 64 + (g0 ^ 4) * 8];
    }
#pragma unroll
    for (int m = 0; m < 2; ++m)
#pragma unroll
      for (int n = 0; n < 4; ++n) {
        acc[m][n] = __builtin_amdgcn_mfma_f32_16x16x32_bf16(a0[m], b0[n], acc[m][n], 0, 0, 0);
        acc[m][n] = __builtin_amdgcn_mfma_f32_16x16x32_bf16(a1[m], b1[n], acc[m][n], 0, 0, 0);
      }
    if constexpr (AF32) {
      if (i + 1 < 16) {   // commit next A tile after MFMA (loads flew under it)
        *(bf16x8*)&As[cur ^ 1][arow * 72 + ac16] = cvt8(x0, x1);
        *(bf16x8*)&As[cur ^ 1][arow * 72 + ac16 + 8] = cvt8(x2, x3);
      }
    }
  }
#pragma unroll
  for (int m = 0; m < 2; ++m)
#pragma unroll
    for (int n = 0; n < 4; ++n)
#pragma unroll
      for (int j = 0; j < 4; ++j) {
        const int row = brow + wr * 32 + m * 16 + l4 * 4 + j;
        const int col = bcol + wc * 64 + n * 16 + l15;
        C[(size_t)row * 1024 + col] = (TC)acc[m][n][j];
      }
}

__global__ __launch_bounds__(256) void gemm_qkv_kernel(
    const float* __restrict__ Aq, const float* __restrict__ Ak, const float* __restrict__ Av,
    const bf16* __restrict__ Bq, const bf16* __restrict__ Bk, const bf16* __restrict__ Bv,
    bf16* __restrict__ Cq, bf16* __restrict__ Ck, bf16* __restrict__ Cv) {
  const int z = blockIdx.z;
  const float* A = (z == 0) ? Aq : (z == 1) ? Ak : Av;
  const bf16* B = (z == 0) ? Bq : (z == 1) ? Bk : Bv;
  bf16* C = (z == 0) ? Cq : (z == 1) ? Ck : Cv;
  gemm_body<true, bf16>(A, B, C, blockIdx.y * 64, blockIdx.x * 128);
}

__global__ __launch_bounds__(256) void gemm_out_kernel(const bf16* __restrict__ A,
                                                       const bf16* __restrict__ B,
                                                       float* __restrict__ C) {
  gemm_body<false, float>(A, B, C, blockIdx.y * 64, blockIdx.x * 128);
}

// ---------------- flash attention, swapped-QK^T in-register softmax ----------------
// S^T = mfma(K,Q): lane owns ONE q-row (q=lane&15), 16 kv values in regs.
// Row reduce = in-reg tree + 2 shfl_xor; scalar m,l per lane; mask = u64/lane from global.
// Rescale skipped when running max doesn't grow (exact). P -> wave-private LDS (b64 stores).
__global__ __launch_bounds__(256) void flash_attn_kernel(
    const bf16* __restrict__ Qp, const bf16* __restrict__ Kp, const bf16* __restrict__ Vp,
    const unsigned int* __restrict__ mwg, bf16* __restrict__ AO) {
  const int h = blockIdx.x;            // XCD = h % 8 -> per-XCD L2 holds 2 heads' K/V
  const int qb = blockIdx.y * 64;
  const int tid = threadIdx.x;
  const int lane = tid & 63, w = tid >> 6;
  const int l15 = lane & 15, l4 = lane >> 4;

  __shared__ __align__(16) bf16 Ks[2][64 * 64];
  __shared__ __align__(16) bf16 Vt[2][64 * 72];
  __shared__ __align__(16) bf16 Ps[4][16 * 72];

  const int qrow = qb + w * 16 + l15;
  const bf16* Qr = Qp + (size_t)qrow * 1024 + h * 64;
  const bf16x8 qf0 = *(const bf16x8*)(Qr + l4 * 8);
  const bf16x8 qf1 = *(const bf16x8*)(Qr + 32 + l4 * 8);
  const unsigned long long* mrow = (const unsigned long long*)(mwg + (size_t)qrow * 64);

  f32x4 oacc[4] = {};
  float m_i = NEG_INF_F, l_i = 0.f;

  const int srow = lane >> 3, sgrp = (lane & 7) ^ srow;   // K gload source indices
  const int vr = tid >> 3, vc8 = (tid & 7) * 8;           // V staging indices
  const int vg0 = ((vr >> 3) ^ (tid & 7)) & 7;            // Vt write group (pass0)
  const int kg0 = l4 ^ (l15 & 7);

  // ---- prologue: prefetch tile 0 ----
  bf16x8 vpre0, vpre1; unsigned long long mpre;
#pragma unroll
  for (int p = 0; p < 2; ++p) {
    const int rb = w * 16 + p * 8;
    gload16(Kp + (size_t)(rb + srow) * 1024 + h * 64 + sgrp * 8, &Ks[0][rb * 64]);
  }
  vpre0 = *(const bf16x8*)(Vp + (size_t)vr * 1024 + h * 64 + vc8);
  vpre1 = *(const bf16x8*)(Vp + (size_t)(vr + 32) * 1024 + h * 64 + vc8);
  mpre = mrow[0];

  for (int t = 0; t < 32; ++t) {
    const int cur = t & 1;
    // commit prefetched V (swizzled transpose) for buf[cur]
#pragma unroll
    for (int j = 0; j < 8; ++j) {
      const int d = vc8 + j;
      Vt[cur][d * 72 + vg0 * 8 + (vr & 7)] = vpre0[j];
      Vt[cur][d * 72 + (vg0 ^ 4) * 8 + (vr & 7)] = vpre1[j];
    }
    const unsigned long long mq = mpre;
    __syncthreads();   // drains K gloads (vmcnt) + LDS writes for buf[cur]

    // prefetch tile t+1 (hidden under compute)
    if (t + 1 < 32) {
      const int kvn = (t + 1) * 64;
#pragma unroll
      for (int p = 0; p < 2; ++p) {
        const int rb = w * 16 + p * 8;
        gload16(Kp + (size_t)(kvn + rb + srow) * 1024 + h * 64 + sgrp * 8,
                &Ks[cur ^ 1][rb * 64]);
      }
      vpre0 = *(const bf16x8*)(Vp + (size_t)(kvn + vr) * 1024 + h * 64 + vc8);
      vpre1 = *(const bf16x8*)(Vp + (size_t)(kvn + vr + 32) * 1024 + h * 64 + vc8);
      mpre = mrow[t + 1];
    }

    // ---- QK^T (swapped): s[g][r] = S[kv=g*16+l4*4+r][q=l15] ----
    f32x4 s[4] = {};
    __builtin_amdgcn_s_setprio(1);
#pragma unroll
    for (int g = 0; g < 4; ++g) {
      const int krow = g * 16 + l15;
      const bf16x8 kf0 = *(const bf16x8*)&Ks[cur][krow * 64 + kg0 * 8];
      s[g] = __builtin_amdgcn_mfma_f32_16x16x32_bf16(kf0, qf0, s[g], 0, 0, 0);
      const bf16x8 kf1 = *(const bf16x8*)&Ks[cur][krow * 64 + (kg0 ^ 4) * 8];
      s[g] = __builtin_amdgcn_mfma_f32_16x16x32_bf16(kf1, qf1, s[g], 0, 0, 0);
    }
    __builtin_amdgcn_s_setprio(0);

    // ---- mask + in-register online softmax (per-lane row q=l15) ----
    float p[16];
#pragma unroll
    for (int g = 0; g < 4; ++g)
#pragma unroll
      for (int r = 0; r < 4; ++r) {
        const int bit = g * 16 + l4 * 4 + r;
        p[g * 4 + r] = ((mq >> bit) & 1ull) ? NEG_INF_F : s[g][r] * 0.125f;
      }
    float tmax = fmaxf(
        fmaxf(fmaxf(fmaxf(p[0], p[1]), fmaxf(p[2], p[3])),
              fmaxf(fmaxf(p[4], p[5]), fmaxf(p[6], p[7]))),
        fmaxf(fmaxf(fmaxf(p[8], p[9]), fmaxf(p[10], p[11])),
              fmaxf(fmaxf(p[12], p[13]), fmaxf(p[14], p[15]))));
    tmax = fmaxf(tmax, __shfl_xor(tmax, 16));
    tmax = fmaxf(tmax, __shfl_xor(tmax, 32));

    const bool skip = (bool)__all(tmax <= m_i);
    const float mn = skip ? m_i : fmaxf(m_i, tmax);
#pragma unroll
    for (int i = 0; i < 16; ++i) p[i] = __expf(p[i] - mn);
    float rs = ((p[0] + p[1]) + (p[2] + p[3])) + ((p[4] + p[5]) + (p[6] + p[7])) +
               (((p[8] + p[9]) + (p[10] + p[11])) + ((p[12] + p[13]) + (p[14] + p[15])));
    rs += __shfl_xor(rs, 16);
    rs += __shfl_xor(rs, 32);
    if (!skip) {
      const float sc = __expf(m_i - mn);
      const float s0 = __shfl(sc, l4 * 4 + 0), s1 = __shfl(sc, l4 * 4 + 1);
      const float s2 = __shfl(sc, l4 * 4 + 2), s3 = __shfl(sc, l4 * 4 + 3);
#pragma unroll
      for (int n = 0; n < 4; ++n) {
        oacc[n][0] *= s0; oacc[n][1] *= s1; oacc[n][2] *= s2; oacc[n][3] *= s3;
      }
      l_i *= sc;
      m_i = mn;
    }
    l_i += rs;

    // P -> wave-private LDS [q=l15][kv], 4 x b64 vector stores
#pragma unroll
    for (int g = 0; g < 4; ++g) {
      bf16x4 pk;
      pk[0] = (bf16)p[g * 4 + 0]; pk[1] = (bf16)p[g * 4 + 1];
      pk[2] = (bf16)p[g * 4 + 2]; pk[3] = (bf16)p[g * 4 + 3];
      *(bf16x4*)&Ps[w][l15 * 72 + g * 16 + l4 * 4] = pk;
    }

    // ---- PV: O += P[16x64] * V[64x64] ----
    const bf16x8 pf0 = *(const bf16x8*)&Ps[w][l15 * 72 + l4 * 8];
    const bf16x8 pf1 = *(const bf16x8*)&Ps[w][l15 * 72 + 32 + l4 * 8];
    __builtin_amdgcn_s_setprio(1);
#pragma unroll
    for (int n = 0; n < 4; ++n) {
      const int d = n * 16 + l15;
      const int vgr = l4 ^ ((2 * n + (l15 >> 3)) & 7);
      const bf16x8 vf0 = *(const bf16x8*)&Vt[cur][d * 72 + vgr * 8];
      oacc[n] = __builtin_amdgcn_mfma_f32_16x16x32_bf16(pf0, vf0, oacc[n], 0, 0, 0);
      const bf16x8 vf1 = *(const bf16x8*)&Vt[cur][d * 72 + (vgr ^ 4) * 8];
      oacc[n] = __builtin_amdgcn_mfma_f32_16x16x32_bf16(pf1, vf1, oacc[n], 0, 0, 0);
    }
    __builtin_amdgcn_s_setprio(0);
  }

  const float lj0 = __shfl(l_i, l4 * 4 + 0), lj1 = __shfl(l_i, l4 * 4 + 1);
  const float lj2 = __shfl(l_i, l4 * 4 + 2), lj3 = __shfl(l_i, l4 * 4 + 3);
#pragma unroll
  for (int n = 0; n < 4; ++n) {
    const size_t base = (size_t)(qb + w * 16) * 1024 + h * 64 + n * 16 + l15;
    AO[base + (size_t)(l4 * 4 + 0) * 1024] = (bf16)(oacc[n][0] / lj0);
    AO[base + (size_t)(l4 * 4 + 1) * 1024] = (bf16)(oacc[n][1] / lj1);
    AO[base + (size_t)(l4 * 4 + 2) * 1024] = (bf16)(oacc[n][2] / lj2);
    AO[base + (size_t)(l4 * 4 + 3) * 1024] = (bf16)(oacc[n][3] / lj3);
  }
}

// ---------------- launch ----------------
extern "C" void kernel_launch(void* const* d_in, const int* in_sizes, int n_in,
                              void* d_out, int out_size, void* d_ws, size_t ws_size,
                              hipStream_t stream) {
  const float* q = (const float*)d_in[0];
  const float* k = (const float*)d_in[1];
  const float* v = (const float*)d_in[2];
  const unsigned char* mask = (const unsigned char*)d_in[3];
  const float* Wq = (const float*)d_in[4];
  const float* Wk = (const float*)d_in[5];
  const float* Wv = (const float*)d_in[6];
  const float* Wo = (const float*)d_in[7];
  float* out = (float*)d_out;

  char* ws = (char*)d_ws;
  unsigned int* flag = (unsigned int*)ws;
  unsigned int* mpacked = (unsigned int*)(ws + OFF_MASK);
  bf16* Wqb = (bf16*)(ws + OFF_WQ);
  bf16* Wkb = (bf16*)(ws + OFF_WK);
  bf16* Wvb = (bf16*)(ws + OFF_WV);
  bf16* Wob = (bf16*)(ws + OFF_WO);
  bf16* Qp = (bf16*)(ws + OFF_QP);
  bf16* Kp = (bf16*)(ws + OFF_KP);
  bf16* Vp = (bf16*)(ws + OFF_VP);
  bf16* AO = (bf16*)(ws + OFF_AO);

  detect_width_kernel<<<1, 256, 0, stream>>>(mask, flag);
  pack_mask_kernel<<<2048, 256, 0, stream>>>(mask, flag, mpacked);
  convert_w_kernel<<<dim3(512, 4), 256, 0, stream>>>(Wq, Wk, Wv, Wo, Wqb, Wkb, Wvb, Wob);
  gemm_qkv_kernel<<<dim3(8, 32, 3), 256, 0, stream>>>(q, k, v, Wqb, Wkb, Wvb, Qp, Kp, Vp);
  flash_attn_kernel<<<dim3(16, 32), 256, 0, stream>>>(Qp, Kp, Vp, mpacked, AO);
  gemm_out_kernel<<<dim3(8, 32), 256, 0, stream>>>(AO, Wob, out);
}